// Round 2
// baseline (17871.159 us; speedup 1.0000x reference)
//
#include <hip/hip_runtime.h>
#include <hip/hip_bf16.h>
#include <cstdint>
#include <cstdio>

// Problem constants
#define B_   64
#define U_   512
#define D_   512
#define H_   640
#define P_   512
#define G4H  2560   // 4*H

typedef __bf16 bf16x8 __attribute__((ext_vector_type(8)));
typedef float  f32x4  __attribute__((ext_vector_type(4)));

// ---------------------------------------------------------------------------
// Weight convert + transpose: W[K][N] f32 -> WT[N'][K] bf16.
// reorder=1 remaps gate-major columns (n = g*640+j) to interleaved (n' = 4j+g)
// so one WG owns all 4 gates of a j-slice in the recurrent step kernel.
__global__ __launch_bounds__(256) void wconv_kernel(
    const float* __restrict__ W, __bf16* __restrict__ WT, int K, int N, int reorder) {
    int tid = blockIdx.x * 256 + threadIdx.x;
    if (tid >= K * N) return;
    int k = tid / N, n = tid % N;
    int np = reorder ? (4 * (n % 640) + (n / 640)) : n;
    WT[(size_t)np * K + k] = (__bf16)W[(size_t)k * N + n];
}

__global__ __launch_bounds__(256) void breorder_kernel(
    const float* __restrict__ b, float* __restrict__ br) {
    int n = blockIdx.x * 256 + threadIdx.x;
    if (n < G4H) br[4 * (n % 640) + (n / 640)] = b[n];
}

// Embedding gather -> bf16, 4 elems/thread
__global__ __launch_bounds__(256) void gather_kernel(
    const int* __restrict__ tokens, const float* __restrict__ embed,
    __bf16* __restrict__ X) {
    int tid = blockIdx.x * 256 + threadIdx.x;       // total B_*U_*D_/4
    int row = tid >> 7;                              // D_/4 = 128 groups per row
    int c4  = (tid & 127) << 2;
    int tok = tokens[row];
    float4 v = *reinterpret_cast<const float4*>(embed + (size_t)tok * D_ + c4);
    union { ushort4 u; __bf16 h[4]; } o;
    o.h[0] = (__bf16)v.x; o.h[1] = (__bf16)v.y; o.h[2] = (__bf16)v.z; o.h[3] = (__bf16)v.w;
    *reinterpret_cast<ushort4*>(X + (size_t)row * D_ + c4) = o.u;
}

__global__ __launch_bounds__(256) void zstate_kernel(
    __bf16* __restrict__ h0, __bf16* __restrict__ h1, float* __restrict__ c) {
    int tid = blockIdx.x * 256 + threadIdx.x;
    if (tid < B_ * H_) { h0[tid] = (__bf16)0.f; h1[tid] = (__bf16)0.f; c[tid] = 0.f; }
}

// ---------------------------------------------------------------------------
// Generic bf16 MFMA GEMM: C[M][N] = A[M][K] @ BT[N][K]^T + bias[N]
// WG = 256 threads (4 waves). WG tile 64x64. Wave w: rows [16w,16w+16), 4 n-tiles.
__global__ __launch_bounds__(256) void gemm_kernel(
    const __bf16* __restrict__ A, const __bf16* __restrict__ BT,
    const float* __restrict__ bias,
    float* __restrict__ Cf, __bf16* __restrict__ Cb,
    int M, int N, int K) {
    const int wv = threadIdx.x >> 6, l = threadIdx.x & 63;
    const int lr = l & 15, lh = l >> 4;
    const int m0 = blockIdx.y * 64 + wv * 16;
    const int n0 = blockIdx.x * 64;

    f32x4 acc[4];
    #pragma unroll
    for (int nt = 0; nt < 4; ++nt) acc[nt] = (f32x4){0.f, 0.f, 0.f, 0.f};

    const __bf16* Ap = A  + (size_t)(m0 + lr) * K + lh * 8;
    const __bf16* Bp = BT + (size_t)(n0 + lr) * K + lh * 8;
    for (int k0 = 0; k0 < K; k0 += 32) {
        bf16x8 af = *reinterpret_cast<const bf16x8*>(Ap + k0);
        #pragma unroll
        for (int nt = 0; nt < 4; ++nt) {
            bf16x8 bfv = *reinterpret_cast<const bf16x8*>(Bp + (size_t)nt * 16 * K + k0);
            acc[nt] = __builtin_amdgcn_mfma_f32_16x16x32_bf16(af, bfv, acc[nt], 0, 0, 0);
        }
    }
    // D layout: row = (lane>>4)*4 + r, col = lane&15
    #pragma unroll
    for (int nt = 0; nt < 4; ++nt) {
        int col = n0 + nt * 16 + lr;
        float bs = bias ? bias[col] : 0.f;
        #pragma unroll
        for (int r = 0; r < 4; ++r) {
            int row = m0 + lh * 4 + r;
            float v = acc[nt][r] + bs;
            if (Cf) Cf[(size_t)row * N + col] = v;
            else    Cb[(size_t)row * N + col] = (__bf16)v;
        }
    }
}

// ---------------------------------------------------------------------------
// One LSTM timestep: z = Z[:,t,:] + h @ Wh ; gates; masked state update.
// Grid: 40 WGs, WG w owns reordered cols [64w, 64w+64) == j in [16w, 16w+16).
// h double-buffered across launches (hin read by all WGs, hout written by owner).
__global__ __launch_bounds__(256) void lstm_step_kernel(
    const __bf16* __restrict__ Z,       // [B_*U_][G4H] bf16, cols reordered 4j+g
    const __bf16* __restrict__ WhT,     // [G4H][H_] reordered rows
    const __bf16* __restrict__ hin,     // [B_][H_]
    __bf16* __restrict__ hout,          // [B_][H_]
    float* __restrict__ c,              // [B_][H_]
    __bf16* __restrict__ Hout,          // [B_*U_][H_]
    const int* __restrict__ plen, int t) {
    __shared__ float zl[64 * 65];       // padded to kill bank conflicts
    const int w  = blockIdx.x;
    const int wv = threadIdx.x >> 6, l = threadIdx.x & 63;
    const int lr = l & 15, lh = l >> 4;

    f32x4 acc[4];
    #pragma unroll
    for (int mt = 0; mt < 4; ++mt) acc[mt] = (f32x4){0.f, 0.f, 0.f, 0.f};

    const int n0 = w * 64 + wv * 16;
    const __bf16* Bp  = WhT + (size_t)(n0 + lr) * H_ + lh * 8;
    const __bf16* Apb = hin + (size_t)lr * H_ + lh * 8;
    for (int k0 = 0; k0 < H_; k0 += 32) {
        bf16x8 bfv = *reinterpret_cast<const bf16x8*>(Bp + k0);
        #pragma unroll
        for (int mt = 0; mt < 4; ++mt) {
            bf16x8 af = *reinterpret_cast<const bf16x8*>(Apb + (size_t)mt * 16 * H_ + k0);
            acc[mt] = __builtin_amdgcn_mfma_f32_16x16x32_bf16(af, bfv, acc[mt], 0, 0, 0);
        }
    }
    // z-tile -> LDS (+ precomputed x-part)
    #pragma unroll
    for (int mt = 0; mt < 4; ++mt) {
        int cl = wv * 16 + lr;
        #pragma unroll
        for (int r = 0; r < 4; ++r) {
            int bb = mt * 16 + lh * 4 + r;
            zl[bb * 65 + cl] = acc[mt][r] +
                (float)Z[((size_t)bb * U_ + t) * G4H + w * 64 + cl];
        }
    }
    __syncthreads();
    // gates + masked update; 1024 (b,j) items over 256 threads
    #pragma unroll
    for (int it = 0; it < 4; ++it) {
        int idx = threadIdx.x + it * 256;
        int bb = idx >> 4, jj = idx & 15;
        int j = w * 16 + jj;
        float zi = zl[bb * 65 + 4 * jj + 0];
        float zf = zl[bb * 65 + 4 * jj + 1];
        float zg = zl[bb * 65 + 4 * jj + 2];
        float zo = zl[bb * 65 + 4 * jj + 3];
        float ig = 1.f / (1.f + __expf(-zi));
        float fg = 1.f / (1.f + __expf(-zf));
        float og = 1.f / (1.f + __expf(-zo));
        float gg = tanhf(zg);
        size_t sidx = (size_t)bb * H_ + j;
        float cold = c[sidx];
        float hold = (float)hin[sidx];
        float cnew = fg * cold + ig * gg;
        float hnew = og * tanhf(cnew);
        bool m = t < plen[bb];
        float c2 = m ? cnew : cold;
        float h2 = m ? hnew : hold;
        c[sidx] = c2;
        __bf16 hb = (__bf16)h2;
        hout[sidx] = hb;
        Hout[((size_t)bb * U_ + t) * H_ + j] = hb;
    }
}

// ---------------------------------------------------------------------------
// In-place LayerNorm over H_=640 per row (bf16 in/out, f32 stats)
__global__ __launch_bounds__(256) void ln_kernel(
    __bf16* __restrict__ X, const float* __restrict__ gamma, const float* __restrict__ beta) {
    __shared__ float s1[256];
    __shared__ float s2[256];
    const int tid = threadIdx.x;
    __bf16* xp = X + (size_t)blockIdx.x * H_;
    float xv[3] = {0.f, 0.f, 0.f};
    float a = 0.f, b = 0.f;
    #pragma unroll
    for (int i = 0; i < 3; ++i) {
        int j = tid + 256 * i;
        if (j < H_) { float v = (float)xp[j]; xv[i] = v; a += v; b += v * v; }
    }
    s1[tid] = a; s2[tid] = b;
    __syncthreads();
    for (int st = 128; st > 0; st >>= 1) {
        if (tid < st) { s1[tid] += s1[tid + st]; s2[tid] += s2[tid + st]; }
        __syncthreads();
    }
    float mean = s1[0] * (1.f / H_);
    float var  = s2[0] * (1.f / H_) - mean * mean;
    float inv  = rsqrtf(var + 0.001f);
    #pragma unroll
    for (int i = 0; i < 3; ++i) {
        int j = tid + 256 * i;
        if (j < H_) xp[j] = (__bf16)((xv[i] - mean) * inv * gamma[j] + beta[j]);
    }
}

// ---------------------------------------------------------------------------
extern "C" void kernel_launch(void* const* d_in, const int* in_sizes, int n_in,
                              void* d_out, int out_size, void* d_ws, size_t ws_size,
                              hipStream_t stream) {
    (void)in_sizes; (void)n_in; (void)out_size;
    const int*   tokens = (const int*)d_in[0];
    const int*   plen   = (const int*)d_in[1];
    const float* embed  = (const float*)d_in[2];
    const float* W0x = (const float*)d_in[3];
    const float* W0h = (const float*)d_in[4];
    const float* b0  = (const float*)d_in[5];
    const float* g0  = (const float*)d_in[6];
    const float* be0 = (const float*)d_in[7];
    const float* P0w = (const float*)d_in[8];
    const float* P0b = (const float*)d_in[9];
    const float* W1x = (const float*)d_in[10];
    const float* W1h = (const float*)d_in[11];
    const float* b1  = (const float*)d_in[12];
    const float* g1  = (const float*)d_in[13];
    const float* be1 = (const float*)d_in[14];
    const float* P1w = (const float*)d_in[15];
    const float* P1b = (const float*)d_in[16];
    float* out = (float*)d_out;

    char* p = (char*)d_ws;
    size_t used = 0;
    auto take = [&](size_t bytes) {
        char* r = p; size_t pad = (bytes + 255) & ~(size_t)255;
        p += pad; used += pad; return r;
    };
    __bf16* WT0x_ = (__bf16*)take((size_t)G4H * D_ * 2);
    __bf16* WT0h_ = (__bf16*)take((size_t)G4H * H_ * 2);
    __bf16* WT1x_ = (__bf16*)take((size_t)G4H * P_ * 2);
    __bf16* WT1h_ = (__bf16*)take((size_t)G4H * H_ * 2);
    __bf16* PT0w_ = (__bf16*)take((size_t)P_ * H_ * 2);
    __bf16* PT1w_ = (__bf16*)take((size_t)P_ * H_ * 2);
    float*  b0r   = (float*)take(G4H * 4);
    float*  b1r   = (float*)take(G4H * 4);
    __bf16* hb0   = (__bf16*)take((size_t)B_ * H_ * 2);
    __bf16* hb1   = (__bf16*)take((size_t)B_ * H_ * 2);
    float*  cst   = (float*)take((size_t)B_ * H_ * 4);
    __bf16* Hbuf  = (__bf16*)take((size_t)B_ * U_ * H_ * 2);   // h outputs, LN'd in place
    __bf16* Z     = (__bf16*)take((size_t)B_ * U_ * G4H * 2);  // pre-activations (bf16)

    if (used > ws_size) {
        fprintf(stderr, "kernel_launch: ws_size too small (%zu < %zu)\n",
                ws_size, used);
        return;
    }
    // Xbf aliases d_out (67 MB f32): Xbf is dead before the final GEMM
    // overwrites d_out completely each call (graph-replay deterministic).
    __bf16* Xbf = (__bf16*)d_out;                              // 33.5 MB of 67 MB

    dim3 blk(256);
    wconv_kernel<<<(D_ * G4H + 255) / 256, blk, 0, stream>>>(W0x, WT0x_, D_, G4H, 1);
    wconv_kernel<<<(H_ * G4H + 255) / 256, blk, 0, stream>>>(W0h, WT0h_, H_, G4H, 1);
    wconv_kernel<<<(P_ * G4H + 255) / 256, blk, 0, stream>>>(W1x, WT1x_, P_, G4H, 1);
    wconv_kernel<<<(H_ * G4H + 255) / 256, blk, 0, stream>>>(W1h, WT1h_, H_, G4H, 1);
    wconv_kernel<<<(H_ * P_ + 255) / 256, blk, 0, stream>>>(P0w, PT0w_, H_, P_, 0);
    wconv_kernel<<<(H_ * P_ + 255) / 256, blk, 0, stream>>>(P1w, PT1w_, H_, P_, 0);
    breorder_kernel<<<10, blk, 0, stream>>>(b0, b0r);
    breorder_kernel<<<10, blk, 0, stream>>>(b1, b1r);
    gather_kernel<<<(B_ * U_ * D_ / 4 + 255) / 256, blk, 0, stream>>>(tokens, embed, Xbf);

    // ---- layer 0 ----
    gemm_kernel<<<dim3(G4H / 64, B_ * U_ / 64), blk, 0, stream>>>(
        Xbf, WT0x_, b0r, nullptr, Z, B_ * U_, G4H, D_);
    zstate_kernel<<<(B_ * H_ + 255) / 256, blk, 0, stream>>>(hb0, hb1, cst);
    for (int t = 0; t < U_; ++t) {
        __bf16* hin  = (t & 1) ? hb1 : hb0;
        __bf16* hout = (t & 1) ? hb0 : hb1;
        lstm_step_kernel<<<40, blk, 0, stream>>>(Z, WT0h_, hin, hout, cst, Hbuf, plen, t);
    }
    ln_kernel<<<B_ * U_, blk, 0, stream>>>(Hbuf, g0, be0);
    gemm_kernel<<<dim3(P_ / 64, B_ * U_ / 64), blk, 0, stream>>>(
        Hbuf, PT0w_, P0b, nullptr, Xbf, B_ * U_, P_, H_);

    // ---- layer 1 ----
    gemm_kernel<<<dim3(G4H / 64, B_ * U_ / 64), blk, 0, stream>>>(
        Xbf, WT1x_, b1r, nullptr, Z, B_ * U_, G4H, P_);
    zstate_kernel<<<(B_ * H_ + 255) / 256, blk, 0, stream>>>(hb0, hb1, cst);
    for (int t = 0; t < U_; ++t) {
        __bf16* hin  = (t & 1) ? hb1 : hb0;
        __bf16* hout = (t & 1) ? hb0 : hb1;
        lstm_step_kernel<<<40, blk, 0, stream>>>(Z, WT1h_, hin, hout, cst, Hbuf, plen, t);
    }
    ln_kernel<<<B_ * U_, blk, 0, stream>>>(Hbuf, g1, be1);
    gemm_kernel<<<dim3(P_ / 64, B_ * U_ / 64), blk, 0, stream>>>(
        Hbuf, PT1w_, P1b, out, nullptr, B_ * U_, P_, H_);
}